// Round 13
// baseline (1885.491 us; speedup 1.0000x reference)
//
#include <hip/hip_runtime.h>
#include <hip/hip_bf16.h>
#include <hip/hip_cooperative_groups.h>
#include <math.h>

namespace cg = cooperative_groups;

// Problem constants
#define Bq   2
#define Lq   2048
#define Dq   256
#define NLq  4
#define Nst  16
#define EDq  512
#define Kq   4
#define DTq  16
#define Vq   32000
#define Rq   (Bq*Lq)          // 4096 rows
#define NCv  64               // scan chunks per batch
#define LCv  (Lq/NCv)         // 32 rows per chunk
#define RPB  4                // rows per block in mid phase

typedef __attribute__((ext_vector_type(8))) __bf16 bf16x8v;
typedef __attribute__((ext_vector_type(4))) float f32x4v;
typedef __attribute__((address_space(1))) const void GV;
typedef __attribute__((address_space(3))) void LV;

__device__ __forceinline__ unsigned short to_bf16(float f) {
    unsigned int u = __float_as_uint(f);
    unsigned int r = (u + 0x7FFFu + ((u >> 16) & 1u)) >> 16;
    return (unsigned short)r;
}
__device__ __forceinline__ float from_bf16(unsigned short u) {
    return __uint_as_float(((unsigned int)u) << 16);
}

// ---------------- f32 -> bf16 weight conversion (4 elems/thread) ----------------
__global__ __launch_bounds__(256) void convert_bf16(const float* __restrict__ in,
                                                    unsigned short* __restrict__ out, int n) {
    int i = (blockIdx.x * 256 + threadIdx.x) * 4;
    if (i + 3 < n) {
        float4 v = *(const float4*)&in[i];
        ushort4 o;
        o.x = to_bf16(v.x); o.y = to_bf16(v.y); o.z = to_bf16(v.z); o.w = to_bf16(v.w);
        *(ushort4*)&out[i] = o;
    }
}

// ---------------- embed (f32 residual) ----------------
__global__ __launch_bounds__(256) void embed_kernel(const int* __restrict__ x,
                                                    const float* __restrict__ et,
                                                    float* __restrict__ h) {
    int r = blockIdx.x;
    int d = threadIdx.x;
    h[r * Dq + d] = et[x[r] * Dq + d];
}

// ---------------- rmsnorm (block per row, D=256), bf16 out ----------------
__global__ __launch_bounds__(256) void rmsnorm_kernel(const float* __restrict__ h,
                                                      const float* __restrict__ w,
                                                      unsigned short* __restrict__ out) {
    int r = blockIdx.x;
    int d = threadIdx.x;
    float v = h[r * Dq + d];
    float ss = v * v;
#pragma unroll
    for (int o = 32; o > 0; o >>= 1) ss += __shfl_down(ss, o);
    __shared__ float sb[4];
    if ((threadIdx.x & 63) == 0) sb[threadIdx.x >> 6] = ss;
    __syncthreads();
    float tot = sb[0] + sb[1] + sb[2] + sb[3];
    float scale = rsqrtf(tot * (1.0f / Dq) + 1e-5f);
    out[r * Dq + d] = to_bf16(v * scale * w[d]);
}

// ---------------- layernorm (block per row, D=256), bf16 out ----------------
__global__ __launch_bounds__(256) void layernorm_kernel(const float* __restrict__ h,
                                                        const float* __restrict__ w,
                                                        const float* __restrict__ b,
                                                        unsigned short* __restrict__ out) {
    int r = blockIdx.x;
    int d = threadIdx.x;
    float v = h[r * Dq + d];
    float s = v, s2 = v * v;
#pragma unroll
    for (int o = 32; o > 0; o >>= 1) { s += __shfl_down(s, o); s2 += __shfl_down(s2, o); }
    __shared__ float sb[8];
    if ((threadIdx.x & 63) == 0) { sb[threadIdx.x >> 6] = s; sb[4 + (threadIdx.x >> 6)] = s2; }
    __syncthreads();
    float S  = sb[0] + sb[1] + sb[2] + sb[3];
    float S2 = sb[4] + sb[5] + sb[6] + sb[7];
    float mu = S * (1.0f / Dq);
    float var = S2 * (1.0f / Dq) - mu * mu;
    out[r * Dq + d] = to_bf16((v - mu) * rsqrtf(var + 1e-5f) * w[d] + b[d]);
}

// ---------------- bf16 MFMA GEMM: C[m,n] (+=) sum_k A[m,k]*W[n,k] (+bias[n]) ----
// m97 structure, tile BMxBN, BK=32, 4 waves, global_load_lds w=16, linear LDS,
// bijective XCD swizzle (m-major).
template<int BM, int BN, typename OT, bool ACC>
__global__ __launch_bounds__(256) void gemm_mfma(const unsigned short* __restrict__ A,
                                                 const unsigned short* __restrict__ W,
                                                 const float* __restrict__ bias,
                                                 OT* __restrict__ C,
                                                 int M, int N, int K) {
    constexpr int WGM = (BM == 128 && BN == 64) ? 4 : 2;
    constexpr int WGN = 4 / WGM;
    constexpr int MR = BM / (WGM * 16);
    constexpr int NR = BN / (WGN * 16);
    constexpr int AR = BM / 64;
    constexpr int BR = BN / 64;
    __shared__ unsigned short As[BM * 32];
    __shared__ unsigned short Bs[BN * 32];

    const int gx = gridDim.x;
    const int nwg = gx * gridDim.y;
    int flat = blockIdx.y * gx + blockIdx.x;
    if ((nwg & 7) == 0) {
        int cpx = nwg >> 3;
        flat = (flat & 7) * cpx + (flat >> 3);
    }
    const int m0 = (flat / gx) * BM, n0 = (flat % gx) * BN;

    const int tid = threadIdx.x;
    const int wid = tid >> 6, lane = tid & 63;
    const int wrow = (wid / WGN) * (BM / WGM);
    const int wcol = (wid % WGN) * (BN / WGN);

    f32x4v acc[MR][NR];
#pragma unroll
    for (int i = 0; i < MR; i++)
#pragma unroll
        for (int j = 0; j < NR; j++) acc[i][j] = (f32x4v){0.f, 0.f, 0.f, 0.f};

    const int srow = lane >> 2;
    const int skoff = (lane & 3) * 8;
    const unsigned short* gA = A + (size_t)(m0 + wid * (16 * AR) + srow) * K + skoff;
    unsigned short* lA = As + wid * (512 * AR) + lane * 8;
    const unsigned short* gW = W + (size_t)(n0 + wid * (16 * BR) + srow) * K + skoff;
    unsigned short* lB = Bs + wid * (512 * BR) + lane * 8;

    const int l15 = lane & 15, lk = (lane >> 4) * 8;

    for (int kt = 0; kt < K; kt += 32) {
        __syncthreads();
#pragma unroll
        for (int p = 0; p < AR; p++)
            __builtin_amdgcn_global_load_lds((GV*)(gA + kt + (size_t)p * 16 * K),
                                             (LV*)(lA + p * 512), 16, 0, 0);
#pragma unroll
        for (int p = 0; p < BR; p++)
            __builtin_amdgcn_global_load_lds((GV*)(gW + kt + (size_t)p * 16 * K),
                                             (LV*)(lB + p * 512), 16, 0, 0);
        __syncthreads();

        bf16x8v a[MR], b[NR];
#pragma unroll
        for (int i = 0; i < MR; i++)
            a[i] = *(const bf16x8v*)&As[(wrow + i * 16 + l15) * 32 + lk];
#pragma unroll
        for (int j = 0; j < NR; j++)
            b[j] = *(const bf16x8v*)&Bs[(wcol + j * 16 + l15) * 32 + lk];
#pragma unroll
        for (int i = 0; i < MR; i++)
#pragma unroll
            for (int j = 0; j < NR; j++)
                acc[i][j] = __builtin_amdgcn_mfma_f32_16x16x32_bf16(a[i], b[j], acc[i][j], 0, 0, 0);
    }

    const int rbase = m0 + wrow + (lane >> 4) * 4;
    const int cbase = n0 + wcol + l15;
#pragma unroll
    for (int i = 0; i < MR; i++) {
#pragma unroll
        for (int j = 0; j < NR; j++) {
            int col = cbase + j * 16;
            float bv = bias ? bias[col] : 0.f;
#pragma unroll
            for (int r = 0; r < 4; r++) {
                int row = rbase + i * 16 + r;
                float v = acc[i][j][r] + bv;
                OT* dst = &C[(size_t)row * N + col];
                if constexpr (__is_same(OT, unsigned short)) {
                    if constexpr (ACC) *dst = to_bf16(v + from_bf16(*dst));
                    else               *dst = to_bf16(v);
                } else {
                    if constexpr (ACC) *dst = v + *dst;
                    else               *dst = v;
                }
            }
        }
    }
}

// ============ cooperative middle: mid_fused + scan1 + combine + scan2 ============
// grid = 1024 blocks x 256 threads (4 blocks/CU). Phase bodies identical to the
// r9 standalone kernels -> bit-identical numerics.
__global__ __launch_bounds__(256, 4) void layer_middle_coop(
        const unsigned short* __restrict__ xz,
        const float* __restrict__ cw, const float* __restrict__ cb,
        const unsigned short* __restrict__ xpw16,
        const float* __restrict__ dtw, const float* __restrict__ dtb,
        const float* __restrict__ A_log, const float* __restrict__ Dp,
        unsigned short* __restrict__ xc, float* __restrict__ dbc,
        unsigned short* __restrict__ dlt,
        float* __restrict__ cA, float* __restrict__ cB, float* __restrict__ cP,
        unsigned short* __restrict__ y) {
    cg::grid_group grid = cg::this_grid();
    const int tid = threadIdx.x;
    const int bid = blockIdx.x;

    // ---- Phase A: conv+silu + xproj + dtproj for rows r0..r0+RPB-1 ----
    {
        const int r0 = bid * RPB;
        const int l0 = r0 & (Lq - 1);
        __shared__ float xcs[RPB][EDq];
        __shared__ float dbs[RPB][16];

#pragma unroll
        for (int ch = 0; ch < 2; ch++) {
            const int e = tid + ch * 256;
            const float4 wv = *(const float4*)&cw[e * 4];
            const float bb = cb[e];
            float x0 = 0.f, x1 = 0.f, x2 = 0.f;
            if (l0 > 0) {
                x0 = from_bf16(xz[(size_t)(r0 - 3) * 1024 + e]);
                x1 = from_bf16(xz[(size_t)(r0 - 2) * 1024 + e]);
                x2 = from_bf16(xz[(size_t)(r0 - 1) * 1024 + e]);
            }
#pragma unroll
            for (int t = 0; t < RPB; t++) {
                float x3 = from_bf16(xz[(size_t)(r0 + t) * 1024 + e]);
                float a = bb;
                a = fmaf(x0, wv.x, a);
                a = fmaf(x1, wv.y, a);
                a = fmaf(x2, wv.z, a);
                a = fmaf(x3, wv.w, a);
                float s = a / (1.0f + __expf(-a));
                xcs[t][e] = s;
                xc[(size_t)(r0 + t) * EDq + e] = to_bf16(s);
                x0 = x1; x1 = x2; x2 = x3;
            }
        }
        __syncthreads();

        const int j = tid >> 2, sub = tid & 3;
        const unsigned short* wr = &xpw16[j * EDq + sub * 128];
#pragma unroll
        for (int t = 0; t < RPB; t++) {
            float part = 0.f;
            if (j < 48) {
                const float* xr = &xcs[t][sub * 128];
                for (int k = 0; k < 128; k += 4) {
                    ushort4 wv = *(const ushort4*)&wr[k];
                    float4 xv = *(const float4*)&xr[k];
                    part = fmaf(from_bf16(wv.x), xv.x, part);
                    part = fmaf(from_bf16(wv.y), xv.y, part);
                    part = fmaf(from_bf16(wv.z), xv.z, part);
                    part = fmaf(from_bf16(wv.w), xv.w, part);
                }
            }
            part += __shfl_xor(part, 1);
            part += __shfl_xor(part, 2);
            if (j < 48 && sub == 0) {
                dbc[(size_t)(r0 + t) * 48 + j] = part;
                if (j < 16) dbs[t][j] = part;
            }
        }
        __syncthreads();

#pragma unroll
        for (int ch = 0; ch < 2; ch++) {
            const int e = tid + ch * 256;
            float wrg[16];
#pragma unroll
            for (int g = 0; g < 4; g++) {
                float4 v = *(const float4*)&dtw[e * 16 + g * 4];
                wrg[g * 4] = v.x; wrg[g * 4 + 1] = v.y; wrg[g * 4 + 2] = v.z; wrg[g * 4 + 3] = v.w;
            }
            const float bb = dtb[e];
#pragma unroll
            for (int t = 0; t < RPB; t++) {
                float a = bb;
#pragma unroll
                for (int k = 0; k < 16; k++) a = fmaf(dbs[t][k], wrg[k], a);
                float sp = (a > 20.f) ? a : log1pf(__expf(a));
                dlt[(size_t)(r0 + t) * EDq + e] = to_bf16(sp);
            }
        }
    }
    grid.sync();

    // ---- Phase B: scan pass 1 ----
    {
        int gid = bid * 256 + tid;
        int sub = gid & 3;
        int e = (gid >> 2) & (EDq - 1);
        int bc = gid >> 11;
        int rbase = bc * LCv;

        float Aa[4];
#pragma unroll
        for (int k = 0; k < 4; k++) Aa[k] = -__expf(A_log[e * 16 + sub * 4 + k]);
        float pA[4] = {1.f, 1.f, 1.f, 1.f};
        float hB[4] = {0.f, 0.f, 0.f, 0.f};

#pragma unroll 4
        for (int t = 0; t < LCv; t++) {
            int r = rbase + t;
            float d = from_bf16(dlt[(size_t)r * EDq + e]);
            float xv = from_bf16(xc[(size_t)r * EDq + e]);
            float dx = d * xv;
            float4 Bm = *(const float4*)&dbc[(size_t)r * 48 + 16 + sub * 4];
            float Bk[4] = {Bm.x, Bm.y, Bm.z, Bm.w};
#pragma unroll
            for (int k = 0; k < 4; k++) {
                float dA = __expf(d * Aa[k]);
                hB[k] = fmaf(dA, hB[k], dx * Bk[k]);
                pA[k] *= dA;
            }
        }
        size_t ob = ((size_t)bc * EDq + e) * 16 + sub * 4;
        *(float4*)&cA[ob] = make_float4(pA[0], pA[1], pA[2], pA[3]);
        *(float4*)&cB[ob] = make_float4(hB[0], hB[1], hB[2], hB[3]);
    }
    grid.sync();

    // ---- Phase C: chunk combine (blocks 0..63 active) ----
    if (bid < 64) {
        int idx = bid * 256 + tid;              // < B*ED*N = 16384
        int en = idx & 8191;
        int b = idx >> 13;
        float hc = 0.f;
        for (int c = 0; c < NCv; c++) {
            size_t base = ((size_t)(b * NCv + c) << 13) + en;
            cP[base] = hc;
            hc = fmaf(cA[base], hc, cB[base]);
        }
    }
    grid.sync();

    // ---- Phase D: scan pass 2 ----
    {
        int gid = bid * 256 + tid;
        int sub = gid & 3;
        int e = (gid >> 2) & (EDq - 1);
        int bc = gid >> 11;
        int rbase = bc * LCv;

        float Aa[4];
#pragma unroll
        for (int k = 0; k < 4; k++) Aa[k] = -__expf(A_log[e * 16 + sub * 4 + k]);
        float hh[4];
        size_t pb = ((size_t)bc * EDq + e) * 16 + sub * 4;
        {
            float4 v = *(const float4*)&cP[pb];
            hh[0] = v.x; hh[1] = v.y; hh[2] = v.z; hh[3] = v.w;
        }
        const float Dv = Dp[e];

#pragma unroll 4
        for (int t = 0; t < LCv; t++) {
            int r = rbase + t;
            float d = from_bf16(dlt[(size_t)r * EDq + e]);
            float xv = from_bf16(xc[(size_t)r * EDq + e]);
            float dx = d * xv;
            float4 Bm = *(const float4*)&dbc[(size_t)r * 48 + 16 + sub * 4];
            float4 Cm = *(const float4*)&dbc[(size_t)r * 48 + 32 + sub * 4];
            float Bk[4] = {Bm.x, Bm.y, Bm.z, Bm.w};
            float Ck[4] = {Cm.x, Cm.y, Cm.z, Cm.w};
            float cacc = 0.f;
#pragma unroll
            for (int k = 0; k < 4; k++) {
                float dA = __expf(d * Aa[k]);
                hh[k] = fmaf(dA, hh[k], dx * Bk[k]);
                cacc = fmaf(hh[k], Ck[k], cacc);
            }
            cacc += __shfl_xor(cacc, 1);
            cacc += __shfl_xor(cacc, 2);
            if (sub == 0) {
                float yv = fmaf(Dv, xv, cacc);
                float zv = from_bf16(xz[(size_t)r * 1024 + EDq + e]);
                float sz = zv / (1.0f + __expf(-zv));
                y[(size_t)r * EDq + e] = to_bf16(yv * sz);
            }
        }
    }
}

// ---------------- launch ----------------
extern "C" void kernel_launch(void* const* d_in, const int* in_sizes, int n_in,
                              void* d_out, int out_size, void* d_ws, size_t ws_size,
                              hipStream_t stream) {
    const int*   x         = (const int*)d_in[0];
    const float* embed_t   = (const float*)d_in[1];
    const float* rms_w     = (const float*)d_in[2];
    const float* in_proj_w = (const float*)d_in[3];
    const float* conv_w    = (const float*)d_in[4];
    const float* conv_b    = (const float*)d_in[5];
    const float* x_proj_w  = (const float*)d_in[6];
    const float* dt_proj_w = (const float*)d_in[7];
    const float* dt_proj_b = (const float*)d_in[8];
    const float* A_log     = (const float*)d_in[9];
    const float* D_p       = (const float*)d_in[10];
    const float* out_proj_w= (const float*)d_in[11];
    const float* norm_w    = (const float*)d_in[12];
    const float* norm_b    = (const float*)d_in[13];
    const float* head_w    = (const float*)d_in[14];
    const float* head_b    = (const float*)d_in[15];
    float* out = (float*)d_out;

    const size_t CSZ = (size_t)Bq * NCv * EDq * Nst;   // 1,048,576 floats (4 MB)

    float* ws = (float*)d_ws;
    float* h    = ws;                           // R*D f32 residual
    float* dbc  = h   + (size_t)Rq * Dq;        // R*48
    float* cA   = dbc + (size_t)Rq * 48;
    float* cB   = cA  + CSZ;
    float* cP   = cB  + CSZ;
    float* fend = cP  + CSZ;

    unsigned short* xz16  = (unsigned short*)fend;            // R*1024
    unsigned short* xc16  = xz16  + (size_t)Rq * 1024;        // R*ED
    unsigned short* dlt16 = xc16  + (size_t)Rq * EDq;         // R*ED
    unsigned short* xin16 = dlt16 + (size_t)Rq * EDq;         // R*D
    unsigned short* yb16  = xin16 + (size_t)Rq * Dq;          // R*ED
    unsigned short* hn16  = yb16  + (size_t)Rq * EDq;         // R*D
    unsigned short* w16i  = hn16  + (size_t)Rq * Dq;          // 4*1024*256
    unsigned short* w16o  = w16i  + (size_t)NLq * 1024 * Dq;  // 4*256*512
    unsigned short* w16xp = w16o  + (size_t)NLq * Dq * EDq;   // 4*48*512
    unsigned short* w16h  = w16xp + (size_t)NLq * 48 * EDq;   // 32000*256

    // weight conversions (per-call, deterministic)
    convert_bf16<<<(NLq * 1024 * Dq) / 1024, 256, 0, stream>>>(in_proj_w, w16i, NLq * 1024 * Dq);
    convert_bf16<<<(NLq * Dq * EDq) / 1024, 256, 0, stream>>>(out_proj_w, w16o, NLq * Dq * EDq);
    convert_bf16<<<(NLq * 48 * EDq) / 1024, 256, 0, stream>>>(x_proj_w, w16xp, NLq * 48 * EDq);
    convert_bf16<<<(Vq * Dq) / 1024, 256, 0, stream>>>(head_w, w16h, Vq * Dq);

    embed_kernel<<<Rq, 256, 0, stream>>>(x, embed_t, h);

    for (int i = 0; i < NLq; i++) {
        rmsnorm_kernel<<<Rq, 256, 0, stream>>>(h, rms_w + i * Dq, xin16);
        gemm_mfma<128, 128, unsigned short, false>
            <<<dim3(1024 / 128, Rq / 128), 256, 0, stream>>>(
            xin16, w16i + (size_t)i * 1024 * Dq, nullptr, xz16, Rq, 1024, Dq);

        // cooperative middle (mid_fused + scan1 + combine + scan2)
        const unsigned short* cxz = xz16;
        const float* ccw  = conv_w + i * EDq * Kq;
        const float* ccb  = conv_b + i * EDq;
        const unsigned short* cxp = w16xp + (size_t)i * 48 * EDq;
        const float* cdtw = dt_proj_w + (size_t)i * EDq * DTq;
        const float* cdtb = dt_proj_b + i * EDq;
        const float* cal  = A_log + i * EDq * Nst;
        const float* cdp  = D_p + i * EDq;
        unsigned short* cxc = xc16;
        float* cdbc = dbc;
        unsigned short* cdlt = dlt16;
        float *ca = cA, *cb = cB, *cp = cP;
        unsigned short* cy = yb16;
        void* args[] = {(void*)&cxz, (void*)&ccw, (void*)&ccb, (void*)&cxp,
                        (void*)&cdtw, (void*)&cdtb, (void*)&cal, (void*)&cdp,
                        (void*)&cxc, (void*)&cdbc, (void*)&cdlt,
                        (void*)&ca, (void*)&cb, (void*)&cp, (void*)&cy};
        hipLaunchCooperativeKernel((const void*)layer_middle_coop,
                                   dim3(Rq / RPB), dim3(256), args, 0, stream);

        gemm_mfma<64, 64, float, true><<<dim3(Dq / 64, Rq / 64), 256, 0, stream>>>(
            yb16, w16o + (size_t)i * Dq * EDq, nullptr, h, Rq, Dq, EDq);
    }

    layernorm_kernel<<<Rq, 256, 0, stream>>>(h, norm_w, norm_b, hn16);
    gemm_mfma<128, 128, float, false><<<dim3(Vq / 128, Rq / 128), 256, 0, stream>>>(
        hn16, w16h, head_b, out, Rq, Vq, Dq);
}

// Round 14
// 630.973 us; speedup vs baseline: 2.9882x; 2.9882x over previous
//
#include <hip/hip_runtime.h>
#include <hip/hip_bf16.h>
#include <math.h>

// Problem constants
#define Bq   2
#define Lq   2048
#define Dq   256
#define NLq  4
#define Nst  16
#define EDq  512
#define Kq   4
#define DTq  16
#define Vq   32000
#define Rq   (Bq*Lq)          // 4096 rows
#define NCv  64               // scan chunks per batch
#define LCv  (Lq/NCv)         // 32 rows per chunk
#define RPB  4                // rows per block in mid_fused

typedef __attribute__((ext_vector_type(8))) __bf16 bf16x8v;
typedef __attribute__((ext_vector_type(4))) float f32x4v;
typedef __attribute__((address_space(1))) const void GV;
typedef __attribute__((address_space(3))) void LV;

__device__ __forceinline__ unsigned short to_bf16(float f) {
    unsigned int u = __float_as_uint(f);
    unsigned int r = (u + 0x7FFFu + ((u >> 16) & 1u)) >> 16;
    return (unsigned short)r;
}
__device__ __forceinline__ float from_bf16(unsigned short u) {
    return __uint_as_float(((unsigned int)u) << 16);
}

// ---------------- fused f32 -> bf16 conversion of all 4 weight tensors ----------
// destinations are contiguous in ws: [w16i | w16o | w16xp | w16h]
__global__ __launch_bounds__(256) void convert_all(const float* __restrict__ w_in,
                                                   const float* __restrict__ w_out,
                                                   const float* __restrict__ w_xp,
                                                   const float* __restrict__ w_head,
                                                   unsigned short* __restrict__ dst) {
    const int S1 = NLq * 1024 * Dq;            // 1,048,576
    const int S2 = S1 + NLq * Dq * EDq;        // 1,572,864
    const int S3 = S2 + NLq * 48 * EDq;        // 1,671,168
    int i = (blockIdx.x * 256 + threadIdx.x) * 4;
    const float* src;
    int off;
    if (i < S1)      { src = w_in;   off = i; }
    else if (i < S2) { src = w_out;  off = i - S1; }
    else if (i < S3) { src = w_xp;   off = i - S2; }
    else             { src = w_head; off = i - S3; }
    float4 v = *(const float4*)&src[off];
    ushort4 o;
    o.x = to_bf16(v.x); o.y = to_bf16(v.y); o.z = to_bf16(v.z); o.w = to_bf16(v.w);
    *(ushort4*)&dst[i] = o;
}

// ---------------- embed (f32 residual) ----------------
__global__ __launch_bounds__(256) void embed_kernel(const int* __restrict__ x,
                                                    const float* __restrict__ et,
                                                    float* __restrict__ h) {
    int r = blockIdx.x;
    int d = threadIdx.x;
    h[r * Dq + d] = et[x[r] * Dq + d];
}

// ---------------- rmsnorm (block per row, D=256), bf16 out ----------------
__global__ __launch_bounds__(256) void rmsnorm_kernel(const float* __restrict__ h,
                                                      const float* __restrict__ w,
                                                      unsigned short* __restrict__ out) {
    int r = blockIdx.x;
    int d = threadIdx.x;
    float v = h[r * Dq + d];
    float ss = v * v;
#pragma unroll
    for (int o = 32; o > 0; o >>= 1) ss += __shfl_down(ss, o);
    __shared__ float sb[4];
    if ((threadIdx.x & 63) == 0) sb[threadIdx.x >> 6] = ss;
    __syncthreads();
    float tot = sb[0] + sb[1] + sb[2] + sb[3];
    float scale = rsqrtf(tot * (1.0f / Dq) + 1e-5f);
    out[r * Dq + d] = to_bf16(v * scale * w[d]);
}

// ---------------- layernorm (block per row, D=256), bf16 out ----------------
__global__ __launch_bounds__(256) void layernorm_kernel(const float* __restrict__ h,
                                                        const float* __restrict__ w,
                                                        const float* __restrict__ b,
                                                        unsigned short* __restrict__ out) {
    int r = blockIdx.x;
    int d = threadIdx.x;
    float v = h[r * Dq + d];
    float s = v, s2 = v * v;
#pragma unroll
    for (int o = 32; o > 0; o >>= 1) { s += __shfl_down(s, o); s2 += __shfl_down(s2, o); }
    __shared__ float sb[8];
    if ((threadIdx.x & 63) == 0) { sb[threadIdx.x >> 6] = s; sb[4 + (threadIdx.x >> 6)] = s2; }
    __syncthreads();
    float S  = sb[0] + sb[1] + sb[2] + sb[3];
    float S2 = sb[4] + sb[5] + sb[6] + sb[7];
    float mu = S * (1.0f / Dq);
    float var = S2 * (1.0f / Dq) - mu * mu;
    out[r * Dq + d] = to_bf16((v - mu) * rsqrtf(var + 1e-5f) * w[d] + b[d]);
}

// ---------------- bf16 MFMA GEMM: C[m,n] (+=) sum_k A[m,k]*W[n,k] (+bias[n]) ----
// m97 structure, tile BMxBN, BK=32, 4 waves, global_load_lds w=16, linear LDS,
// bijective XCD swizzle (m-major).
template<int BM, int BN, typename OT, bool ACC>
__global__ __launch_bounds__(256) void gemm_mfma(const unsigned short* __restrict__ A,
                                                 const unsigned short* __restrict__ W,
                                                 const float* __restrict__ bias,
                                                 OT* __restrict__ C,
                                                 int M, int N, int K) {
    constexpr int WGM = (BM == 128 && BN == 64) ? 4 : 2;
    constexpr int WGN = 4 / WGM;
    constexpr int MR = BM / (WGM * 16);
    constexpr int NR = BN / (WGN * 16);
    constexpr int AR = BM / 64;   // A staging rounds (16 rows/wave/round)
    constexpr int BR = BN / 64;
    __shared__ unsigned short As[BM * 32];
    __shared__ unsigned short Bs[BN * 32];

    const int gx = gridDim.x;
    const int nwg = gx * gridDim.y;
    int flat = blockIdx.y * gx + blockIdx.x;
    if ((nwg & 7) == 0) {
        int cpx = nwg >> 3;
        flat = (flat & 7) * cpx + (flat >> 3);
    }
    const int m0 = (flat / gx) * BM, n0 = (flat % gx) * BN;

    const int tid = threadIdx.x;
    const int wid = tid >> 6, lane = tid & 63;
    const int wrow = (wid / WGN) * (BM / WGM);
    const int wcol = (wid % WGN) * (BN / WGN);

    f32x4v acc[MR][NR];
#pragma unroll
    for (int i = 0; i < MR; i++)
#pragma unroll
        for (int j = 0; j < NR; j++) acc[i][j] = (f32x4v){0.f, 0.f, 0.f, 0.f};

    const int srow = lane >> 2;          // 0..15
    const int skoff = (lane & 3) * 8;    // 0,8,16,24
    const unsigned short* gA = A + (size_t)(m0 + wid * (16 * AR) + srow) * K + skoff;
    unsigned short* lA = As + wid * (512 * AR) + lane * 8;
    const unsigned short* gW = W + (size_t)(n0 + wid * (16 * BR) + srow) * K + skoff;
    unsigned short* lB = Bs + wid * (512 * BR) + lane * 8;

    const int l15 = lane & 15, lk = (lane >> 4) * 8;

    for (int kt = 0; kt < K; kt += 32) {
        __syncthreads();  // previous iteration's ds_reads complete
#pragma unroll
        for (int p = 0; p < AR; p++)
            __builtin_amdgcn_global_load_lds((GV*)(gA + kt + (size_t)p * 16 * K),
                                             (LV*)(lA + p * 512), 16, 0, 0);
#pragma unroll
        for (int p = 0; p < BR; p++)
            __builtin_amdgcn_global_load_lds((GV*)(gW + kt + (size_t)p * 16 * K),
                                             (LV*)(lB + p * 512), 16, 0, 0);
        __syncthreads();  // drains vmcnt(0): staged data visible

        bf16x8v a[MR], b[NR];
#pragma unroll
        for (int i = 0; i < MR; i++)
            a[i] = *(const bf16x8v*)&As[(wrow + i * 16 + l15) * 32 + lk];
#pragma unroll
        for (int j = 0; j < NR; j++)
            b[j] = *(const bf16x8v*)&Bs[(wcol + j * 16 + l15) * 32 + lk];
#pragma unroll
        for (int i = 0; i < MR; i++)
#pragma unroll
            for (int j = 0; j < NR; j++)
                acc[i][j] = __builtin_amdgcn_mfma_f32_16x16x32_bf16(a[i], b[j], acc[i][j], 0, 0, 0);
    }

    // epilogue: C/D layout col=lane&15, row=(lane>>4)*4+reg  [m89-verified]
    const int rbase = m0 + wrow + (lane >> 4) * 4;
    const int cbase = n0 + wcol + l15;
#pragma unroll
    for (int i = 0; i < MR; i++) {
#pragma unroll
        for (int j = 0; j < NR; j++) {
            int col = cbase + j * 16;
            float bv = bias ? bias[col] : 0.f;
#pragma unroll
            for (int r = 0; r < 4; r++) {
                int row = rbase + i * 16 + r;
                float v = acc[i][j][r] + bv;
                OT* dst = &C[(size_t)row * N + col];
                if constexpr (__is_same(OT, unsigned short)) {
                    if constexpr (ACC) *dst = to_bf16(v + from_bf16(*dst));
                    else               *dst = to_bf16(v);
                } else {
                    if constexpr (ACC) *dst = v + *dst;
                    else               *dst = v;
                }
            }
        }
    }
}

// ---------------- fused conv+silu+xproj+dtproj (RPB=4 rows per block) ----------------
__global__ __launch_bounds__(256) void mid_fused(const unsigned short* __restrict__ xz,
                                                 const float* __restrict__ cw,
                                                 const float* __restrict__ cb,
                                                 const unsigned short* __restrict__ xpw16,
                                                 const float* __restrict__ dtw,
                                                 const float* __restrict__ dtb,
                                                 unsigned short* __restrict__ xc,
                                                 float* __restrict__ dbc,
                                                 unsigned short* __restrict__ dlt) {
    const int r0 = blockIdx.x * RPB;
    const int l0 = r0 & (Lq - 1);         // uniform; 0 only at sequence start
    const int tid = threadIdx.x;
    __shared__ float xcs[RPB][EDq];
    __shared__ float dbs[RPB][16];

    // causal depthwise conv K=4 + silu; 2 channels/thread over RPB rows
#pragma unroll
    for (int ch = 0; ch < 2; ch++) {
        const int e = tid + ch * 256;
        const float4 wv = *(const float4*)&cw[e * 4];
        const float bb = cb[e];
        float x0 = 0.f, x1 = 0.f, x2 = 0.f;
        if (l0 > 0) {
            x0 = from_bf16(xz[(size_t)(r0 - 3) * 1024 + e]);
            x1 = from_bf16(xz[(size_t)(r0 - 2) * 1024 + e]);
            x2 = from_bf16(xz[(size_t)(r0 - 1) * 1024 + e]);
        }
#pragma unroll
        for (int t = 0; t < RPB; t++) {
            float x3 = from_bf16(xz[(size_t)(r0 + t) * 1024 + e]);
            float a = bb;
            a = fmaf(x0, wv.x, a);
            a = fmaf(x1, wv.y, a);
            a = fmaf(x2, wv.z, a);
            a = fmaf(x3, wv.w, a);
            float s = a / (1.0f + __expf(-a));
            xcs[t][e] = s;
            xc[(size_t)(r0 + t) * EDq + e] = to_bf16(s);
            x0 = x1; x1 = x2; x2 = x3;
        }
    }
    __syncthreads();

    // x_proj: 48 outputs/row, 4 lanes per output (each covers 128 of K=512)
    const int j = tid >> 2, sub = tid & 3;
    const unsigned short* wr = &xpw16[j * EDq + sub * 128];
#pragma unroll
    for (int t = 0; t < RPB; t++) {
        float part = 0.f;
        if (j < 48) {
            const float* xr = &xcs[t][sub * 128];
            for (int k = 0; k < 128; k += 4) {
                ushort4 wv = *(const ushort4*)&wr[k];
                float4 xv = *(const float4*)&xr[k];
                part = fmaf(from_bf16(wv.x), xv.x, part);
                part = fmaf(from_bf16(wv.y), xv.y, part);
                part = fmaf(from_bf16(wv.z), xv.z, part);
                part = fmaf(from_bf16(wv.w), xv.w, part);
            }
        }
        part += __shfl_xor(part, 1);
        part += __shfl_xor(part, 2);
        if (j < 48 && sub == 0) {
            dbc[(size_t)(r0 + t) * 48 + j] = part;
            if (j < 16) dbs[t][j] = part;
        }
    }
    __syncthreads();

    // dt_proj + softplus; 2 channels/thread over RPB rows
#pragma unroll
    for (int ch = 0; ch < 2; ch++) {
        const int e = tid + ch * 256;
        float wrg[16];
#pragma unroll
        for (int g = 0; g < 4; g++) {
            float4 v = *(const float4*)&dtw[e * 16 + g * 4];
            wrg[g * 4] = v.x; wrg[g * 4 + 1] = v.y; wrg[g * 4 + 2] = v.z; wrg[g * 4 + 3] = v.w;
        }
        const float bb = dtb[e];
#pragma unroll
        for (int t = 0; t < RPB; t++) {
            float a = bb;
#pragma unroll
            for (int k = 0; k < 16; k++) a = fmaf(dbs[t][k], wrg[k], a);
            float sp = (a > 20.f) ? a : log1pf(__expf(a));
            dlt[(size_t)(r0 + t) * EDq + e] = to_bf16(sp);
        }
    }
}

// ---------------- scan pass 1: thread = (chunk, e, n-quad) ----------------
__global__ __launch_bounds__(256) void scan_pass1(const unsigned short* __restrict__ dlt,
                                                  const unsigned short* __restrict__ xc,
                                                  const float* __restrict__ dbc,
                                                  const float* __restrict__ A_log,
                                                  float* __restrict__ cA,
                                                  float* __restrict__ cB) {
    int gid = blockIdx.x * 256 + threadIdx.x;   // < B*NCv*ED*4 = 262144
    int sub = gid & 3;
    int e = (gid >> 2) & (EDq - 1);
    int bc = gid >> 11;                          // b*NCv + c
    int rbase = bc * LCv;

    float Aa[4];
#pragma unroll
    for (int k = 0; k < 4; k++) Aa[k] = -__expf(A_log[e * 16 + sub * 4 + k]);
    float pA[4] = {1.f, 1.f, 1.f, 1.f};
    float hB[4] = {0.f, 0.f, 0.f, 0.f};

#pragma unroll 4
    for (int t = 0; t < LCv; t++) {
        int r = rbase + t;
        float d = from_bf16(dlt[(size_t)r * EDq + e]);
        float xv = from_bf16(xc[(size_t)r * EDq + e]);
        float dx = d * xv;
        float4 Bm = *(const float4*)&dbc[(size_t)r * 48 + 16 + sub * 4];
        float Bk[4] = {Bm.x, Bm.y, Bm.z, Bm.w};
#pragma unroll
        for (int k = 0; k < 4; k++) {
            float dA = __expf(d * Aa[k]);
            hB[k] = fmaf(dA, hB[k], dx * Bk[k]);
            pA[k] *= dA;
        }
    }
    size_t ob = ((size_t)bc * EDq + e) * 16 + sub * 4;
    *(float4*)&cA[ob] = make_float4(pA[0], pA[1], pA[2], pA[3]);
    *(float4*)&cB[ob] = make_float4(hB[0], hB[1], hB[2], hB[3]);
}

// ---------------- scan pass 2 (inlined prefix; no combine kernel) ----------------
// Each thread computes its chunk prefix from cA/cB with the SAME fmaf order the
// old combine kernel used (bit-identical), then recomputes its chunk and emits
// y = (h.C + D*xc)*silu(z) as bf16. All threads of a block share one chunk ->
// no divergence; worst-case block (c=63) adds ~63 L2-latency fmaf steps.
__global__ __launch_bounds__(256) void scan_pass2(const unsigned short* __restrict__ dlt,
                                                  const unsigned short* __restrict__ xc,
                                                  const float* __restrict__ dbc,
                                                  const float* __restrict__ A_log,
                                                  const float* __restrict__ cA,
                                                  const float* __restrict__ cB,
                                                  const float* __restrict__ Dp,
                                                  const unsigned short* __restrict__ xz,
                                                  unsigned short* __restrict__ y) {
    int gid = blockIdx.x * 256 + threadIdx.x;   // < B*NCv*ED*4 = 262144
    int sub = gid & 3;
    int e = (gid >> 2) & (EDq - 1);
    int bc = gid >> 11;
    int c  = bc & (NCv - 1);
    int b0 = bc - c;                             // batch base chunk index
    int rbase = bc * LCv;

    float Aa[4];
#pragma unroll
    for (int k = 0; k < 4; k++) Aa[k] = -__expf(A_log[e * 16 + sub * 4 + k]);

    // prefix over chunks [b0, bc)
    float hh[4] = {0.f, 0.f, 0.f, 0.f};
    {
        size_t base = ((size_t)b0 * EDq + e) * 16 + sub * 4;
#pragma unroll 4
        for (int cc = 0; cc < c; cc++) {
            float4 a4 = *(const float4*)&cA[base];
            float4 b4 = *(const float4*)&cB[base];
            hh[0] = fmaf(a4.x, hh[0], b4.x);
            hh[1] = fmaf(a4.y, hh[1], b4.y);
            hh[2] = fmaf(a4.z, hh[2], b4.z);
            hh[3] = fmaf(a4.w, hh[3], b4.w);
            base += (size_t)EDq * 16;
        }
    }
    const float Dv = Dp[e];

#pragma unroll 4
    for (int t = 0; t < LCv; t++) {
        int r = rbase + t;
        float d = from_bf16(dlt[(size_t)r * EDq + e]);
        float xv = from_bf16(xc[(size_t)r * EDq + e]);
        float dx = d * xv;
        float4 Bm = *(const float4*)&dbc[(size_t)r * 48 + 16 + sub * 4];
        float4 Cm = *(const float4*)&dbc[(size_t)r * 48 + 32 + sub * 4];
        float Bk[4] = {Bm.x, Bm.y, Bm.z, Bm.w};
        float Ck[4] = {Cm.x, Cm.y, Cm.z, Cm.w};
        float cacc = 0.f;
#pragma unroll
        for (int k = 0; k < 4; k++) {
            float dA = __expf(d * Aa[k]);
            hh[k] = fmaf(dA, hh[k], dx * Bk[k]);
            cacc = fmaf(hh[k], Ck[k], cacc);
        }
        cacc += __shfl_xor(cacc, 1);
        cacc += __shfl_xor(cacc, 2);
        if (sub == 0) {
            float yv = fmaf(Dv, xv, cacc);
            float zv = from_bf16(xz[(size_t)r * 1024 + EDq + e]);
            float sz = zv / (1.0f + __expf(-zv));
            y[(size_t)r * EDq + e] = to_bf16(yv * sz);
        }
    }
}

// ---------------- launch ----------------
extern "C" void kernel_launch(void* const* d_in, const int* in_sizes, int n_in,
                              void* d_out, int out_size, void* d_ws, size_t ws_size,
                              hipStream_t stream) {
    const int*   x         = (const int*)d_in[0];
    const float* embed_t   = (const float*)d_in[1];
    const float* rms_w     = (const float*)d_in[2];
    const float* in_proj_w = (const float*)d_in[3];
    const float* conv_w    = (const float*)d_in[4];
    const float* conv_b    = (const float*)d_in[5];
    const float* x_proj_w  = (const float*)d_in[6];
    const float* dt_proj_w = (const float*)d_in[7];
    const float* dt_proj_b = (const float*)d_in[8];
    const float* A_log     = (const float*)d_in[9];
    const float* D_p       = (const float*)d_in[10];
    const float* out_proj_w= (const float*)d_in[11];
    const float* norm_w    = (const float*)d_in[12];
    const float* norm_b    = (const float*)d_in[13];
    const float* head_w    = (const float*)d_in[14];
    const float* head_b    = (const float*)d_in[15];
    float* out = (float*)d_out;

    const size_t CSZ = (size_t)Bq * NCv * EDq * Nst;   // 1,048,576 floats (4 MB)

    float* ws = (float*)d_ws;
    float* h    = ws;                           // R*D f32 residual
    float* dbc  = h   + (size_t)Rq * Dq;        // R*48
    float* cA   = dbc + (size_t)Rq * 48;
    float* cB   = cA  + CSZ;
    float* fend = cB  + CSZ;

    unsigned short* xz16  = (unsigned short*)fend;            // R*1024
    unsigned short* xc16  = xz16  + (size_t)Rq * 1024;        // R*ED
    unsigned short* dlt16 = xc16  + (size_t)Rq * EDq;         // R*ED
    unsigned short* xin16 = dlt16 + (size_t)Rq * EDq;         // R*D
    unsigned short* yb16  = xin16 + (size_t)Rq * Dq;          // R*ED
    unsigned short* hn16  = yb16  + (size_t)Rq * EDq;         // R*D
    unsigned short* w16i  = hn16  + (size_t)Rq * Dq;          // 4*1024*256
    unsigned short* w16o  = w16i  + (size_t)NLq * 1024 * Dq;  // 4*256*512
    unsigned short* w16xp = w16o  + (size_t)NLq * Dq * EDq;   // 4*48*512
    unsigned short* w16h  = w16xp + (size_t)NLq * 48 * EDq;   // 32000*256

    // single fused weight conversion (dst regions contiguous from w16i)
    const int TOTW = NLq * 1024 * Dq + NLq * Dq * EDq + NLq * 48 * EDq + Vq * Dq;
    convert_all<<<TOTW / 1024, 256, 0, stream>>>(in_proj_w, out_proj_w, x_proj_w,
                                                 head_w, w16i);

    embed_kernel<<<Rq, 256, 0, stream>>>(x, embed_t, h);

    for (int i = 0; i < NLq; i++) {
        rmsnorm_kernel<<<Rq, 256, 0, stream>>>(h, rms_w + i * Dq, xin16);
        gemm_mfma<128, 128, unsigned short, false>
            <<<dim3(1024 / 128, Rq / 128), 256, 0, stream>>>(
            xin16, w16i + (size_t)i * 1024 * Dq, nullptr, xz16, Rq, 1024, Dq);
        mid_fused<<<Rq / RPB, 256, 0, stream>>>(
            xz16, conv_w + i * EDq * Kq, conv_b + i * EDq,
            w16xp + (size_t)i * 48 * EDq,
            dt_proj_w + (size_t)i * EDq * DTq, dt_proj_b + i * EDq,
            xc16, dbc, dlt16);
        scan_pass1<<<(Bq * NCv * EDq * 4) / 256, 256, 0, stream>>>(
            dlt16, xc16, dbc, A_log + i * EDq * Nst, cA, cB);
        scan_pass2<<<(Bq * NCv * EDq * 4) / 256, 256, 0, stream>>>(
            dlt16, xc16, dbc, A_log + i * EDq * Nst, cA, cB, D_p + i * EDq, xz16, yb16);
        gemm_mfma<64, 64, float, true><<<dim3(Dq / 64, Rq / 64), 256, 0, stream>>>(
            yb16, w16o + (size_t)i * Dq * EDq, nullptr, h, Rq, Dq, EDq);
    }

    layernorm_kernel<<<Rq, 256, 0, stream>>>(h, norm_w, norm_b, hn16);
    gemm_mfma<128, 128, float, false><<<dim3(Vq / 128, Rq / 128), 256, 0, stream>>>(
        hn16, w16h, head_b, out, Rq, Vq, Dq);
}

// Round 15
// 615.226 us; speedup vs baseline: 3.0647x; 1.0256x over previous
//
#include <hip/hip_runtime.h>
#include <hip/hip_bf16.h>
#include <math.h>

// Problem constants
#define Bq   2
#define Lq   2048
#define Dq   256
#define NLq  4
#define Nst  16
#define EDq  512
#define Kq   4
#define DTq  16
#define Vq   32000
#define Rq   (Bq*Lq)          // 4096 rows
#define NCv  64               // scan chunks per batch
#define LCv  (Lq/NCv)         // 32 rows per chunk
#define RPB  4                // rows per block in mid_fused

typedef __attribute__((ext_vector_type(8))) __bf16 bf16x8v;
typedef __attribute__((ext_vector_type(4))) float f32x4v;
typedef __attribute__((address_space(1))) const void GV;
typedef __attribute__((address_space(3))) void LV;

__device__ __forceinline__ unsigned short to_bf16(float f) {
    unsigned int u = __float_as_uint(f);
    unsigned int r = (u + 0x7FFFu + ((u >> 16) & 1u)) >> 16;
    return (unsigned short)r;
}
__device__ __forceinline__ float from_bf16(unsigned short u) {
    return __uint_as_float(((unsigned int)u) << 16);
}

// ---------------- fused f32 -> bf16 conversion of all 4 weight tensors ----------
// destinations are contiguous in ws: [w16i | w16o | w16xp | w16h]
__global__ __launch_bounds__(256) void convert_all(const float* __restrict__ w_in,
                                                   const float* __restrict__ w_out,
                                                   const float* __restrict__ w_xp,
                                                   const float* __restrict__ w_head,
                                                   unsigned short* __restrict__ dst) {
    const int S1 = NLq * 1024 * Dq;            // 1,048,576
    const int S2 = S1 + NLq * Dq * EDq;        // 1,572,864
    const int S3 = S2 + NLq * 48 * EDq;        // 1,671,168
    int i = (blockIdx.x * 256 + threadIdx.x) * 4;
    const float* src;
    int off;
    if (i < S1)      { src = w_in;   off = i; }
    else if (i < S2) { src = w_out;  off = i - S1; }
    else if (i < S3) { src = w_xp;   off = i - S2; }
    else             { src = w_head; off = i - S3; }
    float4 v = *(const float4*)&src[off];
    ushort4 o;
    o.x = to_bf16(v.x); o.y = to_bf16(v.y); o.z = to_bf16(v.z); o.w = to_bf16(v.w);
    *(ushort4*)&dst[i] = o;
}

// ---------------- embed (f32 residual) ----------------
__global__ __launch_bounds__(256) void embed_kernel(const int* __restrict__ x,
                                                    const float* __restrict__ et,
                                                    float* __restrict__ h) {
    int r = blockIdx.x;
    int d = threadIdx.x;
    h[r * Dq + d] = et[x[r] * Dq + d];
}

// ---------------- rmsnorm (block per row, D=256), bf16 out ----------------
__global__ __launch_bounds__(256) void rmsnorm_kernel(const float* __restrict__ h,
                                                      const float* __restrict__ w,
                                                      unsigned short* __restrict__ out) {
    int r = blockIdx.x;
    int d = threadIdx.x;
    float v = h[r * Dq + d];
    float ss = v * v;
#pragma unroll
    for (int o = 32; o > 0; o >>= 1) ss += __shfl_down(ss, o);
    __shared__ float sb[4];
    if ((threadIdx.x & 63) == 0) sb[threadIdx.x >> 6] = ss;
    __syncthreads();
    float tot = sb[0] + sb[1] + sb[2] + sb[3];
    float scale = rsqrtf(tot * (1.0f / Dq) + 1e-5f);
    out[r * Dq + d] = to_bf16(v * scale * w[d]);
}

// ---------------- layernorm (block per row, D=256), bf16 out ----------------
__global__ __launch_bounds__(256) void layernorm_kernel(const float* __restrict__ h,
                                                        const float* __restrict__ w,
                                                        const float* __restrict__ b,
                                                        unsigned short* __restrict__ out) {
    int r = blockIdx.x;
    int d = threadIdx.x;
    float v = h[r * Dq + d];
    float s = v, s2 = v * v;
#pragma unroll
    for (int o = 32; o > 0; o >>= 1) { s += __shfl_down(s, o); s2 += __shfl_down(s2, o); }
    __shared__ float sb[8];
    if ((threadIdx.x & 63) == 0) { sb[threadIdx.x >> 6] = s; sb[4 + (threadIdx.x >> 6)] = s2; }
    __syncthreads();
    float S  = sb[0] + sb[1] + sb[2] + sb[3];
    float S2 = sb[4] + sb[5] + sb[6] + sb[7];
    float mu = S * (1.0f / Dq);
    float var = S2 * (1.0f / Dq) - mu * mu;
    out[r * Dq + d] = to_bf16((v - mu) * rsqrtf(var + 1e-5f) * w[d] + b[d]);
}

// ---------------- bf16 MFMA GEMM: C[m,n] (+=) sum_k A[m,k]*W[n,k] (+bias[n]) ----
// m97 structure, tile BMxBN, BK=32, 4 waves, global_load_lds w=16, linear LDS,
// bijective XCD swizzle (m-major).
template<int BM, int BN, typename OT, bool ACC>
__global__ __launch_bounds__(256) void gemm_mfma(const unsigned short* __restrict__ A,
                                                 const unsigned short* __restrict__ W,
                                                 const float* __restrict__ bias,
                                                 OT* __restrict__ C,
                                                 int M, int N, int K) {
    constexpr int WGM = (BM == 128 && BN == 64) ? 4 : 2;
    constexpr int WGN = 4 / WGM;
    constexpr int MR = BM / (WGM * 16);
    constexpr int NR = BN / (WGN * 16);
    constexpr int AR = BM / 64;   // A staging rounds (16 rows/wave/round)
    constexpr int BR = BN / 64;
    __shared__ unsigned short As[BM * 32];
    __shared__ unsigned short Bs[BN * 32];

    const int gx = gridDim.x;
    const int nwg = gx * gridDim.y;
    int flat = blockIdx.y * gx + blockIdx.x;
    if ((nwg & 7) == 0) {
        int cpx = nwg >> 3;
        flat = (flat & 7) * cpx + (flat >> 3);
    }
    const int m0 = (flat / gx) * BM, n0 = (flat % gx) * BN;

    const int tid = threadIdx.x;
    const int wid = tid >> 6, lane = tid & 63;
    const int wrow = (wid / WGN) * (BM / WGM);
    const int wcol = (wid % WGN) * (BN / WGN);

    f32x4v acc[MR][NR];
#pragma unroll
    for (int i = 0; i < MR; i++)
#pragma unroll
        for (int j = 0; j < NR; j++) acc[i][j] = (f32x4v){0.f, 0.f, 0.f, 0.f};

    const int srow = lane >> 2;          // 0..15
    const int skoff = (lane & 3) * 8;    // 0,8,16,24
    const unsigned short* gA = A + (size_t)(m0 + wid * (16 * AR) + srow) * K + skoff;
    unsigned short* lA = As + wid * (512 * AR) + lane * 8;
    const unsigned short* gW = W + (size_t)(n0 + wid * (16 * BR) + srow) * K + skoff;
    unsigned short* lB = Bs + wid * (512 * BR) + lane * 8;

    const int l15 = lane & 15, lk = (lane >> 4) * 8;

    for (int kt = 0; kt < K; kt += 32) {
        __syncthreads();  // previous iteration's ds_reads complete
#pragma unroll
        for (int p = 0; p < AR; p++)
            __builtin_amdgcn_global_load_lds((GV*)(gA + kt + (size_t)p * 16 * K),
                                             (LV*)(lA + p * 512), 16, 0, 0);
#pragma unroll
        for (int p = 0; p < BR; p++)
            __builtin_amdgcn_global_load_lds((GV*)(gW + kt + (size_t)p * 16 * K),
                                             (LV*)(lB + p * 512), 16, 0, 0);
        __syncthreads();  // drains vmcnt(0): staged data visible

        bf16x8v a[MR], b[NR];
#pragma unroll
        for (int i = 0; i < MR; i++)
            a[i] = *(const bf16x8v*)&As[(wrow + i * 16 + l15) * 32 + lk];
#pragma unroll
        for (int j = 0; j < NR; j++)
            b[j] = *(const bf16x8v*)&Bs[(wcol + j * 16 + l15) * 32 + lk];
#pragma unroll
        for (int i = 0; i < MR; i++)
#pragma unroll
            for (int j = 0; j < NR; j++)
                acc[i][j] = __builtin_amdgcn_mfma_f32_16x16x32_bf16(a[i], b[j], acc[i][j], 0, 0, 0);
    }

    // epilogue: C/D layout col=lane&15, row=(lane>>4)*4+reg  [m89-verified]
    const int rbase = m0 + wrow + (lane >> 4) * 4;
    const int cbase = n0 + wcol + l15;
#pragma unroll
    for (int i = 0; i < MR; i++) {
#pragma unroll
        for (int j = 0; j < NR; j++) {
            int col = cbase + j * 16;
            float bv = bias ? bias[col] : 0.f;
#pragma unroll
            for (int r = 0; r < 4; r++) {
                int row = rbase + i * 16 + r;
                float v = acc[i][j][r] + bv;
                OT* dst = &C[(size_t)row * N + col];
                if constexpr (__is_same(OT, unsigned short)) {
                    if constexpr (ACC) *dst = to_bf16(v + from_bf16(*dst));
                    else               *dst = to_bf16(v);
                } else {
                    if constexpr (ACC) *dst = v + *dst;
                    else               *dst = v;
                }
            }
        }
    }
}

// ---------------- fused conv+silu+xproj+dtproj (RPB=4 rows per block) ----------------
__global__ __launch_bounds__(256) void mid_fused(const unsigned short* __restrict__ xz,
                                                 const float* __restrict__ cw,
                                                 const float* __restrict__ cb,
                                                 const unsigned short* __restrict__ xpw16,
                                                 const float* __restrict__ dtw,
                                                 const float* __restrict__ dtb,
                                                 unsigned short* __restrict__ xc,
                                                 float* __restrict__ dbc,
                                                 unsigned short* __restrict__ dlt) {
    const int r0 = blockIdx.x * RPB;
    const int l0 = r0 & (Lq - 1);         // uniform; 0 only at sequence start
    const int tid = threadIdx.x;
    __shared__ float xcs[RPB][EDq];
    __shared__ float dbs[RPB][16];

    // causal depthwise conv K=4 + silu; 2 channels/thread over RPB rows
#pragma unroll
    for (int ch = 0; ch < 2; ch++) {
        const int e = tid + ch * 256;
        const float4 wv = *(const float4*)&cw[e * 4];
        const float bb = cb[e];
        float x0 = 0.f, x1 = 0.f, x2 = 0.f;
        if (l0 > 0) {
            x0 = from_bf16(xz[(size_t)(r0 - 3) * 1024 + e]);
            x1 = from_bf16(xz[(size_t)(r0 - 2) * 1024 + e]);
            x2 = from_bf16(xz[(size_t)(r0 - 1) * 1024 + e]);
        }
#pragma unroll
        for (int t = 0; t < RPB; t++) {
            float x3 = from_bf16(xz[(size_t)(r0 + t) * 1024 + e]);
            float a = bb;
            a = fmaf(x0, wv.x, a);
            a = fmaf(x1, wv.y, a);
            a = fmaf(x2, wv.z, a);
            a = fmaf(x3, wv.w, a);
            float s = a / (1.0f + __expf(-a));
            xcs[t][e] = s;
            xc[(size_t)(r0 + t) * EDq + e] = to_bf16(s);
            x0 = x1; x1 = x2; x2 = x3;
        }
    }
    __syncthreads();

    // x_proj: 48 outputs/row, 4 lanes per output (each covers 128 of K=512)
    const int j = tid >> 2, sub = tid & 3;
    const unsigned short* wr = &xpw16[j * EDq + sub * 128];
#pragma unroll
    for (int t = 0; t < RPB; t++) {
        float part = 0.f;
        if (j < 48) {
            const float* xr = &xcs[t][sub * 128];
            for (int k = 0; k < 128; k += 4) {
                ushort4 wv = *(const ushort4*)&wr[k];
                float4 xv = *(const float4*)&xr[k];
                part = fmaf(from_bf16(wv.x), xv.x, part);
                part = fmaf(from_bf16(wv.y), xv.y, part);
                part = fmaf(from_bf16(wv.z), xv.z, part);
                part = fmaf(from_bf16(wv.w), xv.w, part);
            }
        }
        part += __shfl_xor(part, 1);
        part += __shfl_xor(part, 2);
        if (j < 48 && sub == 0) {
            dbc[(size_t)(r0 + t) * 48 + j] = part;
            if (j < 16) dbs[t][j] = part;
        }
    }
    __syncthreads();

    // dt_proj + softplus; 2 channels/thread over RPB rows
#pragma unroll
    for (int ch = 0; ch < 2; ch++) {
        const int e = tid + ch * 256;
        float wrg[16];
#pragma unroll
        for (int g = 0; g < 4; g++) {
            float4 v = *(const float4*)&dtw[e * 16 + g * 4];
            wrg[g * 4] = v.x; wrg[g * 4 + 1] = v.y; wrg[g * 4 + 2] = v.z; wrg[g * 4 + 3] = v.w;
        }
        const float bb = dtb[e];
#pragma unroll
        for (int t = 0; t < RPB; t++) {
            float a = bb;
#pragma unroll
            for (int k = 0; k < 16; k++) a = fmaf(dbs[t][k], wrg[k], a);
            float sp = (a > 20.f) ? a : log1pf(__expf(a));
            dlt[(size_t)(r0 + t) * EDq + e] = to_bf16(sp);
        }
    }
}

// ---------------- scan pass 1: thread = (chunk, e, n-quad) ----------------
__global__ __launch_bounds__(256) void scan_pass1(const unsigned short* __restrict__ dlt,
                                                  const unsigned short* __restrict__ xc,
                                                  const float* __restrict__ dbc,
                                                  const float* __restrict__ A_log,
                                                  float* __restrict__ cA,
                                                  float* __restrict__ cB) {
    int gid = blockIdx.x * 256 + threadIdx.x;   // < B*NCv*ED*4 = 262144
    int sub = gid & 3;
    int e = (gid >> 2) & (EDq - 1);
    int bc = gid >> 11;                          // b*NCv + c
    int rbase = bc * LCv;

    float Aa[4];
#pragma unroll
    for (int k = 0; k < 4; k++) Aa[k] = -__expf(A_log[e * 16 + sub * 4 + k]);
    float pA[4] = {1.f, 1.f, 1.f, 1.f};
    float hB[4] = {0.f, 0.f, 0.f, 0.f};

#pragma unroll 4
    for (int t = 0; t < LCv; t++) {
        int r = rbase + t;
        float d = from_bf16(dlt[(size_t)r * EDq + e]);
        float xv = from_bf16(xc[(size_t)r * EDq + e]);
        float dx = d * xv;
        float4 Bm = *(const float4*)&dbc[(size_t)r * 48 + 16 + sub * 4];
        float Bk[4] = {Bm.x, Bm.y, Bm.z, Bm.w};
#pragma unroll
        for (int k = 0; k < 4; k++) {
            float dA = __expf(d * Aa[k]);
            hB[k] = fmaf(dA, hB[k], dx * Bk[k]);
            pA[k] *= dA;
        }
    }
    size_t ob = ((size_t)bc * EDq + e) * 16 + sub * 4;
    *(float4*)&cA[ob] = make_float4(pA[0], pA[1], pA[2], pA[3]);
    *(float4*)&cB[ob] = make_float4(hB[0], hB[1], hB[2], hB[3]);
}

// ---------------- scan chunk combine (sequential over NCv chunks) ----------------
__global__ __launch_bounds__(256) void scan_combine(const float* __restrict__ cA,
                                                    const float* __restrict__ cB,
                                                    float* __restrict__ cP) {
    int idx = blockIdx.x * 256 + threadIdx.x;  // < B*ED*N = 16384
    int en = idx & 8191;                        // e*16+n
    int b = idx >> 13;
    float hc = 0.f;
    for (int c = 0; c < NCv; c++) {
        size_t base = ((size_t)(b * NCv + c) << 13) + en;
        cP[base] = hc;
        hc = fmaf(cA[base], hc, cB[base]);
    }
}

// ---------------- scan pass 2: recompute with prefix; y = (h.C + D*xc)*silu(z) ----
__global__ __launch_bounds__(256) void scan_pass2(const unsigned short* __restrict__ dlt,
                                                  const unsigned short* __restrict__ xc,
                                                  const float* __restrict__ dbc,
                                                  const float* __restrict__ A_log,
                                                  const float* __restrict__ cP,
                                                  const float* __restrict__ Dp,
                                                  const unsigned short* __restrict__ xz,
                                                  unsigned short* __restrict__ y) {
    int gid = blockIdx.x * 256 + threadIdx.x;   // < B*NCv*ED*4 = 262144
    int sub = gid & 3;
    int e = (gid >> 2) & (EDq - 1);
    int bc = gid >> 11;
    int rbase = bc * LCv;

    float Aa[4];
#pragma unroll
    for (int k = 0; k < 4; k++) Aa[k] = -__expf(A_log[e * 16 + sub * 4 + k]);
    float hh[4];
    size_t pb = ((size_t)bc * EDq + e) * 16 + sub * 4;
    {
        float4 v = *(const float4*)&cP[pb];
        hh[0] = v.x; hh[1] = v.y; hh[2] = v.z; hh[3] = v.w;
    }
    const float Dv = Dp[e];

#pragma unroll 4
    for (int t = 0; t < LCv; t++) {
        int r = rbase + t;
        float d = from_bf16(dlt[(size_t)r * EDq + e]);
        float xv = from_bf16(xc[(size_t)r * EDq + e]);
        float dx = d * xv;
        float4 Bm = *(const float4*)&dbc[(size_t)r * 48 + 16 + sub * 4];
        float4 Cm = *(const float4*)&dbc[(size_t)r * 48 + 32 + sub * 4];
        float Bk[4] = {Bm.x, Bm.y, Bm.z, Bm.w};
        float Ck[4] = {Cm.x, Cm.y, Cm.z, Cm.w};
        float cacc = 0.f;
#pragma unroll
        for (int k = 0; k < 4; k++) {
            float dA = __expf(d * Aa[k]);
            hh[k] = fmaf(dA, hh[k], dx * Bk[k]);
            cacc = fmaf(hh[k], Ck[k], cacc);
        }
        cacc += __shfl_xor(cacc, 1);
        cacc += __shfl_xor(cacc, 2);
        if (sub == 0) {
            float yv = fmaf(Dv, xv, cacc);
            float zv = from_bf16(xz[(size_t)r * 1024 + EDq + e]);
            float sz = zv / (1.0f + __expf(-zv));
            y[(size_t)r * EDq + e] = to_bf16(yv * sz);
        }
    }
}

// ---------------- launch ----------------
extern "C" void kernel_launch(void* const* d_in, const int* in_sizes, int n_in,
                              void* d_out, int out_size, void* d_ws, size_t ws_size,
                              hipStream_t stream) {
    const int*   x         = (const int*)d_in[0];
    const float* embed_t   = (const float*)d_in[1];
    const float* rms_w     = (const float*)d_in[2];
    const float* in_proj_w = (const float*)d_in[3];
    const float* conv_w    = (const float*)d_in[4];
    const float* conv_b    = (const float*)d_in[5];
    const float* x_proj_w  = (const float*)d_in[6];
    const float* dt_proj_w = (const float*)d_in[7];
    const float* dt_proj_b = (const float*)d_in[8];
    const float* A_log     = (const float*)d_in[9];
    const float* D_p       = (const float*)d_in[10];
    const float* out_proj_w= (const float*)d_in[11];
    const float* norm_w    = (const float*)d_in[12];
    const float* norm_b    = (const float*)d_in[13];
    const float* head_w    = (const float*)d_in[14];
    const float* head_b    = (const float*)d_in[15];
    float* out = (float*)d_out;

    const size_t CSZ = (size_t)Bq * NCv * EDq * Nst;   // 1,048,576 floats (4 MB)

    float* ws = (float*)d_ws;
    float* h    = ws;                           // R*D f32 residual
    float* dbc  = h   + (size_t)Rq * Dq;        // R*48
    float* cA   = dbc + (size_t)Rq * 48;
    float* cB   = cA  + CSZ;
    float* cP   = cB  + CSZ;
    float* fend = cP  + CSZ;

    unsigned short* xz16  = (unsigned short*)fend;            // R*1024
    unsigned short* xc16  = xz16  + (size_t)Rq * 1024;        // R*ED
    unsigned short* dlt16 = xc16  + (size_t)Rq * EDq;         // R*ED
    unsigned short* xin16 = dlt16 + (size_t)Rq * EDq;         // R*D
    unsigned short* yb16  = xin16 + (size_t)Rq * Dq;          // R*ED
    unsigned short* hn16  = yb16  + (size_t)Rq * EDq;         // R*D
    unsigned short* w16i  = hn16  + (size_t)Rq * Dq;          // 4*1024*256
    unsigned short* w16o  = w16i  + (size_t)NLq * 1024 * Dq;  // 4*256*512
    unsigned short* w16xp = w16o  + (size_t)NLq * Dq * EDq;   // 4*48*512
    unsigned short* w16h  = w16xp + (size_t)NLq * 48 * EDq;   // 32000*256

    // single fused weight conversion (dst regions contiguous from w16i)
    const int TOTW = NLq * 1024 * Dq + NLq * Dq * EDq + NLq * 48 * EDq + Vq * Dq;
    convert_all<<<TOTW / 1024, 256, 0, stream>>>(in_proj_w, out_proj_w, x_proj_w,
                                                 head_w, w16i);

    embed_kernel<<<Rq, 256, 0, stream>>>(x, embed_t, h);

    for (int i = 0; i < NLq; i++) {
        rmsnorm_kernel<<<Rq, 256, 0, stream>>>(h, rms_w + i * Dq, xin16);
        gemm_mfma<128, 128, unsigned short, false>
            <<<dim3(1024 / 128, Rq / 128), 256, 0, stream>>>(
            xin16, w16i + (size_t)i * 1024 * Dq, nullptr, xz16, Rq, 1024, Dq);
        mid_fused<<<Rq / RPB, 256, 0, stream>>>(
            xz16, conv_w + i * EDq * Kq, conv_b + i * EDq,
            w16xp + (size_t)i * 48 * EDq,
            dt_proj_w + (size_t)i * EDq * DTq, dt_proj_b + i * EDq,
            xc16, dbc, dlt16);
        scan_pass1<<<(Bq * NCv * EDq * 4) / 256, 256, 0, stream>>>(
            dlt16, xc16, dbc, A_log + i * EDq * Nst, cA, cB);
        scan_combine<<<(Bq * EDq * Nst) / 256, 256, 0, stream>>>(cA, cB, cP);
        scan_pass2<<<(Bq * NCv * EDq * 4) / 256, 256, 0, stream>>>(
            dlt16, xc16, dbc, A_log + i * EDq * Nst, cP, D_p + i * EDq, xz16, yb16);
        gemm_mfma<64, 64, float, true><<<dim3(Dq / 64, Rq / 64), 256, 0, stream>>>(
            yb16, w16o + (size_t)i * Dq * EDq, nullptr, h, Rq, Dq, EDq);
    }

    layernorm_kernel<<<Rq, 256, 0, stream>>>(h, norm_w, norm_b, hn16);
    gemm_mfma<128, 128, float, false><<<dim3(Vq / 128, Rq / 128), 256, 0, stream>>>(
        hn16, w16h, head_b, out, Rq, Vq, Dq);
}